// Round 5
// baseline (37.464 us; speedup 1.0000x reference)
//
#include <hip/hip_runtime.h>
#include <hip/hip_bf16.h>
#include <math.h>

namespace {
constexpr int B = 4;
constexpr int S = 4096;
constexpr int H = 2048;
constexpr int DR = 3;          // depth
constexpr int KSEL = 1365;     // int(4096/3)
constexpr int NBLK1 = 2048;    // blocks in score kernel
constexpr int NWAVE = NBLK1 * 4;          // 8192 waves, 2 tokens each
constexpr unsigned FONE = 0x3F800000u;    // bits of 1.0f
typedef float fx4 __attribute__((ext_vector_type(4)));  // native vec for nontemporal builtin
}

// ---------------------------------------------------------------------------
// K1: raw[d][t] = dot(hidden[t,:], w[d,:]); sc = sigmoid(raw) (exp-form, f32).
//     No LDS, no barriers: weights (24 KiB) read from global -> L1-hot;
//     hidden streamed with nontemporal loads (no cache pollution).
//     Per-wave loss partials written plane-major: partials[d*NWAVE + gw].
// ---------------------------------------------------------------------------
__global__ __launch_bounds__(256, 4) void ecr_scores(const float* __restrict__ hid,
                                                     const float* __restrict__ w,
                                                     unsigned* __restrict__ keys,
                                                     float* __restrict__ partials) {
    const int wave = threadIdx.x >> 6;
    const int lane = threadIdx.x & 63;
    const int gw = blockIdx.x * 4 + wave;             // 0..8191
    const int t0 = gw * 2;                            // flat token = b*S+s
    const fx4* w4 = reinterpret_cast<const fx4*>(w);
    const fx4* h40 = reinterpret_cast<const fx4*>(hid) + (size_t)t0 * (H / 4);
    const fx4* h41 = h40 + (H / 4);

    float a00 = 0.f, a01 = 0.f, a02 = 0.f;            // token 0, depths 0..2
    float a10 = 0.f, a11 = 0.f, a12 = 0.f;            // token 1
#pragma unroll
    for (int j = 0; j < 8; ++j) {
        const int idx = j * 64 + lane;
        const fx4 hv0 = __builtin_nontemporal_load(h40 + idx);
        const fx4 hv1 = __builtin_nontemporal_load(h41 + idx);
        const fx4 w0 = w4[idx];                       // row 0 (L1-hot)
        const fx4 w1 = w4[idx + H / 4];               // row 1
        const fx4 w2 = w4[idx + H / 2];               // row 2
        a00 = fmaf(hv0.x, w0.x, a00); a10 = fmaf(hv1.x, w0.x, a10);
        a00 = fmaf(hv0.y, w0.y, a00); a10 = fmaf(hv1.y, w0.y, a10);
        a00 = fmaf(hv0.z, w0.z, a00); a10 = fmaf(hv1.z, w0.z, a10);
        a00 = fmaf(hv0.w, w0.w, a00); a10 = fmaf(hv1.w, w0.w, a10);
        a01 = fmaf(hv0.x, w1.x, a01); a11 = fmaf(hv1.x, w1.x, a11);
        a01 = fmaf(hv0.y, w1.y, a01); a11 = fmaf(hv1.y, w1.y, a11);
        a01 = fmaf(hv0.z, w1.z, a01); a11 = fmaf(hv1.z, w1.z, a11);
        a01 = fmaf(hv0.w, w1.w, a01); a11 = fmaf(hv1.w, w1.w, a11);
        a02 = fmaf(hv0.x, w2.x, a02); a12 = fmaf(hv1.x, w2.x, a12);
        a02 = fmaf(hv0.y, w2.y, a02); a12 = fmaf(hv1.y, w2.y, a12);
        a02 = fmaf(hv0.z, w2.z, a02); a12 = fmaf(hv1.z, w2.z, a12);
        a02 = fmaf(hv0.w, w2.w, a02); a12 = fmaf(hv1.w, w2.w, a12);
    }
#pragma unroll
    for (int off = 32; off >= 1; off >>= 1) {         // 64-lane butterfly x6
        a00 += __shfl_xor(a00, off); a01 += __shfl_xor(a01, off);
        a02 += __shfl_xor(a02, off); a10 += __shfl_xor(a10, off);
        a11 += __shfl_xor(a11, off); a12 += __shfl_xor(a12, off);
    }
    if (lane == 0) {
        const float s00 = 1.0f / (1.0f + expf(-a00));
        const float s01 = 1.0f / (1.0f + expf(-a01));
        const float s02 = 1.0f / (1.0f + expf(-a02));
        const float s10 = 1.0f / (1.0f + expf(-a10));
        const float s11 = 1.0f / (1.0f + expf(-a11));
        const float s12 = 1.0f / (1.0f + expf(-a12));
        uint2 kk;
        kk.x = __float_as_uint(s00);
        kk.y = __float_as_uint(s10);
        *reinterpret_cast<uint2*>(keys + t0) = kk;    // t0 even -> 8B aligned
        partials[0 * NWAVE + gw] = 1.0f / (1.0f + expf(-s00)) + 1.0f / (1.0f + expf(-s10));
        partials[1 * NWAVE + gw] = 1.0f / (1.0f + expf(-s01)) + 1.0f / (1.0f + expf(-s11));
        partials[2 * NWAVE + gw] = 1.0f / (1.0f + expf(-s02)) + 1.0f / (1.0f + expf(-s12));
    }
}

// ---------------------------------------------------------------------------
// K2: per-batch exact top-KSEL (value desc, index asc). Fast path: if
//     count(key == 1.0f) >= KSEL (saturated sigmoid data), v*=1.0f directly;
//     else branch-uniform bitwise binary search. Stable tie rank via shuffle
//     prefix scan. Block 0 fuses the balancing-loss reduction.
// ---------------------------------------------------------------------------
__global__ __launch_bounds__(512) void ecr_select(const unsigned* __restrict__ keys,
                                                  const float* __restrict__ partials,
                                                  float* __restrict__ out) {
    const int b = blockIdx.x;
    const int t = threadIdx.x;
    const int wave = t >> 6;
    const int lane = t & 63;

    __shared__ int wsum[2][8];
    __shared__ int wscan[8];

    // each thread holds 8 consecutive keys in registers (index order preserved)
    const uint4* kp = reinterpret_cast<const uint4*>(keys + b * S + t * 8);
    const uint4 ka = kp[0], kb = kp[1];
    unsigned kr[8] = {ka.x, ka.y, ka.z, ka.w, kb.x, kb.y, kb.z, kb.w};

    // ---- fast path probe: count keys == 1.0f ----
    int c = 0;
#pragma unroll
    for (int i = 0; i < 8; ++i) c += (kr[i] == FONE);
#pragma unroll
    for (int off = 32; off >= 1; off >>= 1) c += __shfl_xor(c, off);
    if (lane == 0) wsum[0][wave] = c;
    __syncthreads();
    int tot1 = 0;
#pragma unroll
    for (int w = 0; w < 8; ++w) tot1 += wsum[0][w];

    unsigned vstar;
    int m;                                            // ties accepted (lowest index)
    if (tot1 >= KSEL) {                               // block-uniform decision
        vstar = FONE;                                 // nothing can exceed 1.0f
        m = KSEL;
    } else {
        // ---- general bitwise binary search, 1 barrier per iteration ----
        unsigned v = 0;
        int pb = 1;
        for (int bit = 29; bit >= 0; --bit) {
            const unsigned cand = v | (1u << bit);
            int cc = 0;
#pragma unroll
            for (int i = 0; i < 8; ++i) cc += (kr[i] >= cand);
#pragma unroll
            for (int off = 32; off >= 1; off >>= 1) cc += __shfl_xor(cc, off);
            if (lane == 0) wsum[pb][wave] = cc;
            __syncthreads();
            int tot = 0;
#pragma unroll
            for (int w = 0; w < 8; ++w) tot += wsum[pb][w];
            if (tot >= KSEL) v = cand;
            pb ^= 1;
        }
        vstar = v;
        int cg = 0;
#pragma unroll
        for (int i = 0; i < 8; ++i) cg += (kr[i] > vstar);
#pragma unroll
        for (int off = 32; off >= 1; off >>= 1) cg += __shfl_xor(cg, off);
        if (lane == 0) wsum[pb][wave] = cg;
        __syncthreads();
        int g = 0;
#pragma unroll
        for (int w = 0; w < 8; ++w) g += wsum[pb][w];
        m = KSEL - g;
    }

    // ---- stable tie rank via prefix scan of per-thread tie counts ----
    int tc = 0;
#pragma unroll
    for (int i = 0; i < 8; ++i) tc += (kr[i] == vstar);
    int sc = tc;                                      // inclusive wave scan
#pragma unroll
    for (int off = 1; off <= 32; off <<= 1) {
        const int o = __shfl_up(sc, off);
        if (lane >= off) sc += o;
    }
    if (lane == 63) wscan[wave] = sc;                 // wave totals
    __syncthreads();
    int wbase = 0;
    for (int w = 0; w < wave; ++w) wbase += wscan[w];
    int rank = wbase + (sc - tc);                     // rank of this thread's first tie

    // ---- emit depth + masks ----
    float dep[8], f1[8];
#pragma unroll
    for (int i = 0; i < 8; ++i) {
        int sel;
        if (kr[i] > vstar) sel = 1;
        else if (kr[i] == vstar) { sel = (rank < m) ? 1 : 0; ++rank; }
        else sel = 0;
        dep[i] = sel ? 3.0f : 1.0f;
        f1[i] = sel ? 1.0f : 0.0f;
    }
    float* depth = out;                               // [B*S]
    float* masks = out + B * S + 1;                   // [DR][B*S] (base misaligned)
    float4* dp4 = reinterpret_cast<float4*>(depth + b * S + t * 8);
    dp4[0] = make_float4(dep[0], dep[1], dep[2], dep[3]);
    dp4[1] = make_float4(dep[4], dep[5], dep[6], dep[7]);
    const int mb = b * S + t * 8;
#pragma unroll
    for (int i = 0; i < 8; ++i) {
        masks[0 * B * S + mb + i] = 1.0f;
        masks[1 * B * S + mb + i] = f1[i];
        masks[2 * B * S + mb + i] = f1[i];
    }

    // ---- block 0: fused balancing-loss reduction (plane-major partials) ----
    if (b == 0) {
        __shared__ double red[3][8];
        const float4* p4 = reinterpret_cast<const float4*>(partials);
        double a0 = 0.0, a1 = 0.0, a2 = 0.0;
        for (int i = t; i < NWAVE / 4; i += 512) {    // 2048 float4 per plane
            const float4 v0 = p4[i];
            const float4 v1 = p4[NWAVE / 4 + i];
            const float4 v2 = p4[NWAVE / 2 + i];
            a0 += (double)v0.x + (double)v0.y + (double)v0.z + (double)v0.w;
            a1 += (double)v1.x + (double)v1.y + (double)v1.z + (double)v1.w;
            a2 += (double)v2.x + (double)v2.y + (double)v2.z + (double)v2.w;
        }
#pragma unroll
        for (int off = 32; off >= 1; off >>= 1) {
            a0 += __shfl_xor(a0, off);
            a1 += __shfl_xor(a1, off);
            a2 += __shfl_xor(a2, off);
        }
        if (lane == 0) { red[0][wave] = a0; red[1][wave] = a1; red[2][wave] = a2; }
        __syncthreads();
        if (t == 0) {
            double s0 = 0.0, s1 = 0.0, s2 = 0.0;
#pragma unroll
            for (int w = 0; w < 8; ++w) { s0 += red[0][w]; s1 += red[1][w]; s2 += red[2][w]; }
            const double n = (double)(B * S);
            const double lt = log(1.0 / 3.0);
            double l = (lt - log(s0 / n)) + (lt - log(s1 / n)) + (lt - log(s2 / n));
            out[B * S] = (float)(l * (1.0 / 3.0) / 3.0);
        }
    }
}

extern "C" void kernel_launch(void* const* d_in, const int* in_sizes, int n_in,
                              void* d_out, int out_size, void* d_ws, size_t ws_size,
                              hipStream_t stream) {
    const float* hid = (const float*)d_in[0];     // [B,S,H] f32
    const float* w   = (const float*)d_in[1];     // [DR,H] f32
    float* out = (float*)d_out;                   // depth[B*S] | loss | masks[DR*B*S]

    unsigned* keys  = (unsigned*)d_ws;                                   // B*S uint (64 KiB)
    float* partials = (float*)((char*)d_ws + (size_t)B * S * sizeof(unsigned)); // 3*NWAVE f32 (96 KiB)

    ecr_scores<<<NBLK1, 256, 0, stream>>>(hid, w, keys, partials);
    ecr_select<<<B, 512, 0, stream>>>(keys, partials, out);
}